// Round 1
// 215.038 us; speedup vs baseline: 1.0344x; 1.0344x over previous
//
#include <hip/hip_runtime.h>
#include <hip/hip_bf16.h>

// R9: latency theory — R8's 24-wave config (VGPR capped 85, compiled to 40)
// forced the compiler to sink per-kb weight loads -> ~2-deep L2 pipeline,
// both pipes <23% busy. Revert to MROWS=64 / 2 blocks/CU (R7 geometry, 16
// waves/CU) but launch_bounds(512,4) -> VGPR cap 128: full-layer weight
// fragments (64-72 VGPR) held in flight, next layer's weights issued before
// the current epilogue+barrier, biases/w4 hoisted ahead of their use.
// Predict: fused 118 -> ~90us, MfmaUtil 19 -> ~26%, VGPR ~110-128.

#define NB 65536
#define MROWS 64   // row tile (mt=4 x 16)
#define XSTR 296   // 592B row: %16==0, 16B-unit stride 37 (odd) -> 2-way max (free)
#define HSTR 264   // 528B row: %16==0, 16B-unit stride 33 (odd) -> 2-way max (free)

typedef __attribute__((ext_vector_type(8))) short short8;
typedef __attribute__((ext_vector_type(4))) short short4v;
typedef __attribute__((ext_vector_type(4))) float f32x4;

__device__ __forceinline__ float bf2f(unsigned short u){
  union { unsigned int i; float f; } x; x.i = ((unsigned int)u) << 16; return x.f;
}
__device__ __forceinline__ unsigned short f2bf(float f){
  unsigned int x = __float_as_uint(f);
  x += 0x7fffu + ((x >> 16) & 1u);   // RNE
  return (unsigned short)(x >> 16);
}
__device__ __forceinline__ float ldval(const void* p, int idx, int isbf16){
  return isbf16 ? bf2f(((const unsigned short*)p)[idx]) : ((const float*)p)[idx];
}

// wave-0 dtype sniff: low short of dword groups. bf16 -> N(0,1) exponents;
// fp32 -> random mantissa bits (~9% in range). Returns via LDS flag.
__device__ __forceinline__ int block_sniff(const void* obs, int tid, int* sflag){
  if (tid < 64) {
    unsigned short u = ((const unsigned short*)obs)[tid * 2];
    int e = (u >> 7) & 0xFF;
    unsigned long long m = __ballot(e >= 110 && e <= 132);
    if (tid == 0) *sflag = (__popcll(m) >= 32) ? 1 : 0;
  }
  __syncthreads();
  return *sflag;
}

struct KParams {
  const void* obs;
  const void* act;
  const unsigned short* w1t[2];   // swizzled [task][g16][kb9][l16][quad][8]
  const unsigned short* w2t[2];   // swizzled [task][g16][kb8][l16][quad][8]
  const unsigned short* w3t[2];
  const void* b1[2];
  const void* b2[2];
  const void* b3[2];
  const void* w4[2];
  const void* b4[2];
  const int* counts;
  const int* perm;
  void* out;
};

// ---- routing task: exact input precision ----
__device__ __forceinline__ int task_of(const void* obs, int b, int isbf16){
  float v0, v1, v2;
  if (isbf16) {
    short4v u = *(const short4v*)((const unsigned short*)obs + b * 256 + 252);
    v0 = bf2f((unsigned short)u[1]); v1 = bf2f((unsigned short)u[2]); v2 = bf2f((unsigned short)u[3]);
  } else {
    f32x4 u = *(const f32x4*)((const float*)obs + b * 256 + 252);
    v0 = u[1]; v1 = u[2]; v2 = u[3];
  }
  int t = 0; float m = v0;
  if (v1 > m) { m = v1; t = 1; }   // strict > => first-occurrence argmax (jnp)
  if (v2 > m) { t = 2; }
  return t;
}

// ---- K1: blocks 0..599 = weight prep (swizzled B-frag layout); blocks
// 600..855 = per-block task histogram (plain stores overwrite ws poison) ----
__global__ void prep_count(const void* q1W1, const void* q1W2, const void* q1W3,
                           const void* q2W1, const void* q2W2, const void* q2W3,
                           const void* obs, unsigned short* out,
                           int* hist, unsigned char* tasks){
  __shared__ int sflag;
  int tid = threadIdx.x;
  int isbf16 = block_sniff(obs, tid, &sflag);
  if (blockIdx.x >= 600) {             // ---- count role ----
    __shared__ int h[3];
    if (tid < 3) h[tid] = 0;
    __syncthreads();
    int blk = blockIdx.x - 600;
    int b = blk * 256 + tid;
    int t = task_of(obs, b, isbf16);
    tasks[b] = (unsigned char)t;
    atomicAdd(&h[t], 1);
    __syncthreads();
    if (tid < 3) hist[blk * 3 + tid] = h[tid];
    return;
  }
  // ---- prep role: thread writes 8 consecutive swizzled shorts ----
  int gid8 = (blockIdx.x * 256 + tid) * 8;
  int net = gid8 / 614400;
  int idx = gid8 - net * 614400;
  const void* W1 = net ? q2W1 : q1W1;
  const void* W2 = net ? q2W2 : q1W2;
  const void* W3 = net ? q2W3 : q1W3;
  short8 sv;
  if (idx < 221184) {                  // W1t: KC=9, per task 16*9*512=73728
    int t = idx / 73728; int i = idx - t * 73728;
    int g = i / 4608;  int r = i - g * 4608;
    int kb = r >> 9;   int q2 = r & 511;
    int l16 = q2 >> 5; int rem = q2 & 31;
    int n = g * 16 + l16;
    int k = kb * 32 + (rem & ~7);
    #pragma unroll
    for (int j = 0; j < 8; j++) {
      int kk = k + j;
      sv[j] = (kk < 264) ? (short)f2bf(ldval(W1, (t * 264 + kk) * 256 + n, isbf16)) : (short)0;
    }
  } else if (idx < 417792) {           // W2t: KC=8, per task 16*8*512=65536
    int j0 = idx - 221184;
    int t = j0 >> 16; int i = j0 & 65535;
    int g = i >> 12;  int r = i & 4095;
    int kb = r >> 9;  int q2 = r & 511;
    int l16 = q2 >> 5; int rem = q2 & 31;
    int n = g * 16 + l16;
    int k = kb * 32 + (rem & ~7);
    #pragma unroll
    for (int j = 0; j < 8; j++)
      sv[j] = (short)f2bf(ldval(W2, t * 65536 + (k + j) * 256 + n, isbf16));
  } else {                             // W3t
    int j0 = idx - 417792;
    int t = j0 >> 16; int i = j0 & 65535;
    int g = i >> 12;  int r = i & 4095;
    int kb = r >> 9;  int q2 = r & 511;
    int l16 = q2 >> 5; int rem = q2 & 31;
    int n = g * 16 + l16;
    int k = kb * 32 + (rem & ~7);
    #pragma unroll
    for (int j = 0; j < 8; j++)
      sv[j] = (short)f2bf(ldval(W3, t * 65536 + (k + j) * 256 + n, isbf16));
  }
  *(short8*)(out + net * 614400 + idx) = sv;
}

// ---- K2: scatter, atomic-free cross-block prefix from hists ----
__global__ void route_scatter(const unsigned char* __restrict__ tasks,
                              const int* __restrict__ hist,
                              int* counts, int* perm){
  __shared__ int sh[3][256];
  __shared__ int totals[3], pres[3], base[3], zz[3];
  int tid = threadIdx.x;
  int blk = blockIdx.x;
  sh[0][tid] = hist[tid * 3 + 0];
  sh[1][tid] = hist[tid * 3 + 1];
  sh[2][tid] = hist[tid * 3 + 2];
  if (tid < 3) zz[tid] = 0;
  __syncthreads();
  if (tid < 3) {
    int tot = 0, pre = 0;
    for (int b = 0; b < 256; b++) {
      int v = sh[tid][b];
      if (b < blk) pre += v;
      tot += v;
    }
    totals[tid] = tot; pres[tid] = pre;
  }
  __syncthreads();
  if (tid < 3) {
    int a0 = ((totals[0] + MROWS - 1) / MROWS) * MROWS;
    int a1 = ((totals[1] + MROWS - 1) / MROWS) * MROWS;
    int off = (tid == 0) ? 0 : (tid == 1) ? a0 : a0 + a1;
    base[tid] = off + pres[tid];
    if (blk == 0) counts[tid] = totals[tid];
  }
  __syncthreads();
  int b = blk * 256 + tid;
  int t = tasks[b];
  int r = atomicAdd(&zz[t], 1);
  perm[base[t] + r] = b;
}

// ---- weight fragments for one layer, fully resident in VGPRs ----
template<int KC> struct BF { short8 v[KC][2]; };

template<int KC>
__device__ __forceinline__ void load_bf(BF<KC>& f, const unsigned short* __restrict__ wt,
                                        int wave, int quad, int l16){
  const unsigned short* wg = wt + (wave * 2) * (KC * 512) + l16 * 32 + quad * 8;
  #pragma unroll
  for (int kb = 0; kb < KC; ++kb) {
    f.v[kb][0] = *(const short8*)(wg + kb * 512);
    f.v[kb][1] = *(const short8*)(wg + KC * 512 + kb * 512);
  }
}

// ---- MFMA loop only; acc initialized via kb==0 (no live acc between layers) ----
template<int KC>
__device__ __forceinline__ void mfma_layer(const unsigned short* __restrict__ lin, int lstride,
                                           const BF<KC>& f, f32x4 acc[4][2],
                                           int quad, int l16){
  const f32x4 z = {0.f, 0.f, 0.f, 0.f};
  #pragma unroll
  for (int kb = 0; kb < KC; ++kb) {
    short8 afr[4];
    int ko = kb * 32 + quad * 8;
    #pragma unroll
    for (int mt = 0; mt < 4; mt++)
      afr[mt] = *(const short8*)(lin + (mt * 16 + l16) * lstride + ko);
    #pragma unroll
    for (int mt = 0; mt < 4; mt++)
      #pragma unroll
      for (int nt = 0; nt < 2; nt++)
        acc[mt][nt] = __builtin_amdgcn_mfma_f32_16x16x32_bf16(
            afr[mt], f.v[kb][nt], (kb == 0) ? z : acc[mt][nt], 0, 0, 0);
  }
}

// ---- bias+relu+bf16 store to LDS; C/D: col=lane&15, row=quad*4+r ----
__device__ __forceinline__ void epilogue(f32x4 acc[4][2], float bv0, float bv1,
                                         unsigned short* lout, int quad, int l16, int nbase){
  #pragma unroll
  for (int mt = 0; mt < 4; mt++)
    #pragma unroll
    for (int nt = 0; nt < 2; nt++) {
      float bv = nt ? bv1 : bv0;
      f32x4 a = acc[mt][nt];
      #pragma unroll
      for (int r = 0; r < 4; r++) {
        float v = fmaxf(a[r] + bv, 0.f);
        lout[(mt * 16 + quad * 4 + r) * HSTR + nbase + nt * 16 + l16] = f2bf(v);
      }
    }
}

// ---- fused: 64-row task-uniform tile, 512 thr / 8 waves; LDS 71,680B ->
// 2 blocks/CU = 16 waves/CU; VGPR cap 128 (full-layer weight pipeline) ----
__global__ __launch_bounds__(512, 4) void fused_kernel(KParams p){
  __shared__ unsigned short X[MROWS * XSTR];   // 37,888 B ; reused as HB after L1
  __shared__ unsigned short HA[MROWS * HSTR];  // 33,792 B  (total 71,680)
  unsigned short* HB = X;
  int* sflag = (int*)HA;                       // aliased: HA unused until L1 epi

  int tid = threadIdx.x;
  int net = blockIdx.y;
  int p0  = blockIdx.x * MROWS;
  int wave = tid >> 6, lane = tid & 63, quad = lane >> 4, l16 = lane & 15;
  int nbase = wave * 32;   // each of 8 waves owns 32 output cols

  // task/segment first (3 small loads), then issue L1 weights immediately:
  // w1t is always bf16, so the issue does NOT wait on the dtype sniff and
  // the ~400cy L2 latency drains under sniff + X staging + barrier.
  int c0 = p.counts[0], c1 = p.counts[1], c2 = p.counts[2];
  int off1 = ((c0 + MROWS - 1) / MROWS) * MROWS;
  int off2 = off1 + ((c1 + MROWS - 1) / MROWS) * MROWS;
  int task  = (p0 >= off2) ? 2 : ((p0 >= off1) ? 1 : 0);
  int segend = (task == 0) ? c0 : (task == 1) ? off1 + c1 : off2 + c2;

  BF<9> f1;
  load_bf<9>(f1, p.w1t[net] + task * 73728, wave, quad, l16);

  int isbf16 = block_sniff(p.obs, tid, sflag);
  int bsz = isbf16 ? 2 : 4;

  // stage X: 8 threads/row (all 512 threads); validity is arithmetic
  {
    int srow = tid >> 3, seg = tid & 7;
    int pos = p0 + srow;
    int r = (pos < segend) ? p.perm[pos] : -1;
    #pragma unroll
    for (int j = 0; j < 5; ++j) {
      int c = seg + 8 * j;
      if (c <= 35) {
        short8 sv = {0,0,0,0,0,0,0,0};
        if (r >= 0 && c < 33) {
          if (isbf16) {
            const unsigned short* src = (c < 32) ? ((const unsigned short*)p.obs + r * 256 + c * 8)
                                                 : ((const unsigned short*)p.act + r * 8);
            sv = *(const short8*)src;
          } else {
            const float* src = (c < 32) ? ((const float*)p.obs + r * 256 + c * 8)
                                        : ((const float*)p.act + r * 8);
            f32x4 a = *(const f32x4*)src;
            f32x4 b = *(const f32x4*)(src + 4);
            #pragma unroll
            for (int q = 0; q < 4; q++) { sv[q] = (short)f2bf(a[q]); sv[4 + q] = (short)f2bf(b[q]); }
          }
        }
        *(short8*)(X + srow * XSTR + c * 8) = sv;
      }
    }
  }
  __syncthreads();

  f32x4 acc[4][2];

  // ---- L1 ---- (bias issued before MFMAs; f2 issued before epilogue+barrier)
  const char* b1p = (const char*)p.b1[net] + task * 256 * bsz;
  float bva0 = ldval(b1p, nbase + l16, isbf16);
  float bva1 = ldval(b1p, nbase + 16 + l16, isbf16);
  mfma_layer<9>(X, XSTR, f1, acc, quad, l16);
  BF<8> f2;
  load_bf<8>(f2, p.w2t[net] + task * 65536, wave, quad, l16);
  epilogue(acc, bva0, bva1, HA, quad, l16, nbase);
  __syncthreads();

  // ---- L2 ----
  const char* b2p = (const char*)p.b2[net] + task * 256 * bsz;
  float bvb0 = ldval(b2p, nbase + l16, isbf16);
  float bvb1 = ldval(b2p, nbase + 16 + l16, isbf16);
  mfma_layer<8>(HA, HSTR, f2, acc, quad, l16);
  BF<8> f3;
  load_bf<8>(f3, p.w3t[net] + task * 65536, wave, quad, l16);
  epilogue(acc, bvb0, bvb1, HB, quad, l16, nbase);
  __syncthreads();

  // ---- L3 ---- (w4 slice + b4 prefetched before epilogue+barrier)
  const char* b3p = (const char*)p.b3[net] + task * 256 * bsz;
  float bvc0 = ldval(b3p, nbase + l16, isbf16);
  float bvc1 = ldval(b3p, nbase + 16 + l16, isbf16);
  mfma_layer<8>(HB, HSTR, f3, acc, quad, l16);

  int seg = tid & 7, row = tid >> 3;
  float wv[32];
  if (isbf16) {
    const unsigned short* w4p = (const unsigned short*)p.w4[net] + task * 256 + seg * 32;
    #pragma unroll
    for (int q = 0; q < 4; q++) {
      short8 t = *(const short8*)(w4p + q * 8);
      #pragma unroll
      for (int j = 0; j < 8; j++) wv[q * 8 + j] = bf2f((unsigned short)t[j]);
    }
  } else {
    const float* w4p = (const float*)p.w4[net] + task * 256 + seg * 32;
    #pragma unroll
    for (int q = 0; q < 8; q++) {
      f32x4 a = *(const f32x4*)(w4p + q * 4);
      #pragma unroll
      for (int j = 0; j < 4; j++) wv[q * 4 + j] = a[j];
    }
  }
  float b4v = ldval(p.b4[net], task, isbf16);
  epilogue(acc, bvc0, bvc1, HA, quad, l16, nbase);
  __syncthreads();

  // ---- L4: y = h3 . w4 + b4  (8 threads/row, 3-level shuffle) ----
  {
    float s = 0.f;
    #pragma unroll
    for (int kk = 0; kk < 32; kk += 8) {
      short8 hv = *(const short8*)(HA + row * HSTR + seg * 32 + kk);
      #pragma unroll
      for (int j = 0; j < 8; j++)
        s += bf2f((unsigned short)hv[j]) * wv[kk + j];
    }
    s += __shfl_xor(s, 1);
    s += __shfl_xor(s, 2);
    s += __shfl_xor(s, 4);
    if (seg == 0) {
      int pos = p0 + row;
      if (pos < segend) {
        int r = p.perm[pos];
        float y = s + b4v;
        if (isbf16) ((unsigned short*)p.out)[net * NB + r] = f2bf(y);
        else        ((float*)p.out)[net * NB + r] = y;
      }
    }
  }
}

extern "C" void kernel_launch(void* const* d_in, const int* in_sizes, int n_in,
                              void* d_out, int out_size, void* d_ws, size_t ws_size,
                              hipStream_t stream) {
  char* ws = (char*)d_ws;
  int* counts  = (int*)ws;                                // 3 ints @0 (K2 stores)
  int* hist    = (int*)(ws + 64);                         // 256*3 ints (K1 stores)
  unsigned char* tasks = (unsigned char*)(ws + 3200);     // 65536 B (K1 stores)
  int* perm    = (int*)(ws + 68800);                      // <=65662 ints (K2 stores)
  unsigned short* wts  = (unsigned short*)(ws + 331520);  // 2*614400 bf16 (K1 stores)

  const void* obs = d_in[0];
  const void* act = d_in[1];

  prep_count<<<856, 256, 0, stream>>>(d_in[2], d_in[4], d_in[6],
                                      d_in[10], d_in[12], d_in[14],
                                      obs, wts, hist, tasks);
  route_scatter<<<256, 256, 0, stream>>>(tasks, hist, counts, perm);

  KParams kp;
  kp.obs = obs; kp.act = act;
  for (int q = 0; q < 2; q++) {
    int base = 2 + q * 8;
    kp.b1[q] = d_in[base + 1];
    kp.b2[q] = d_in[base + 3];
    kp.b3[q] = d_in[base + 5];
    kp.w4[q] = d_in[base + 6];
    kp.b4[q] = d_in[base + 7];
    kp.w1t[q] = wts + q * 614400;
    kp.w2t[q] = wts + q * 614400 + 221184;
    kp.w3t[q] = wts + q * 614400 + 417792;
  }
  kp.counts = counts; kp.perm = perm;
  kp.out = d_out;

  // 1026 tiles of 64 rows covers worst-case per-task padding (sum ceil <= 1026)
  fused_kernel<<<dim3(1026, 2), 512, 0, stream>>>(kp);
}